// Round 11
// baseline (37960.910 us; speedup 1.0000x reference)
//
#include <hip/hip_runtime.h>
#include <hip/hip_bf16.h>
#include <math.h>

#define NCB 8
#define CBS 1024
#define HID 512
#define NB 8
#define TLAT 4096

__global__ void rb_sentinel(float* out, float v)
{
    out[threadIdx.x] = v;
}

// ---------------- encoder conv: stride 2, pad 7, K=15, ELU — f64 interior, f32 storage ----
template<int CIN, int COUT, int LIN>
__global__ __launch_bounds__(256)
void rb_enc(const float* __restrict__ x, const float* __restrict__ w,
            const float* __restrict__ bias, float* __restrict__ y)
{
    constexpr int LOUT = LIN / 2;
    const int t   = blockIdx.x * 512 + threadIdx.x * 2;   // outputs t, t+1
    const int co0 = blockIdx.y * 4;
    const int b   = blockIdx.z;
    const float* xb = x + (size_t)b * CIN * LIN;

    double acc[4][2];
#pragma unroll
    for (int c = 0; c < 4; ++c) acc[c][0] = acc[c][1] = (double)bias[co0 + c];

    for (int ci = 0; ci < CIN; ++ci) {
        const float* xc = xb + (size_t)ci * LIN;
        const float* wc = w + ((size_t)co0 * CIN + ci) * 15;
#pragma unroll
        for (int k = 0; k < 15; ++k) {
            const int xi = 2 * t + k - 7;
            const double x0 = ((unsigned)xi       < (unsigned)LIN) ? (double)xc[xi]     : 0.0;
            const double x1 = ((unsigned)(xi + 2) < (unsigned)LIN) ? (double)xc[xi + 2] : 0.0;
#pragma unroll
            for (int c = 0; c < 4; ++c) {
                const double wv = (double)wc[c * CIN * 15 + k];
                acc[c][0] = fma(wv, x0, acc[c][0]);
                acc[c][1] = fma(wv, x1, acc[c][1]);
            }
        }
    }
#pragma unroll
    for (int c = 0; c < 4; ++c) {
        float* yp = y + ((size_t)b * COUT + co0 + c) * LOUT + t;
        const double a0 = acc[c][0], a1 = acc[c][1];
        yp[0] = (float)(a0 > 0.0 ? a0 : expm1(a0));
        yp[1] = (float)(a1 > 0.0 ? a1 : expm1(a1));
    }
}

// ---------------- decoder ConvTranspose1d: k=15, s=2, p=7, op=1 (f32) ----------------
template<int CIN, int COUT, int LIN, int CO_PER, int ACT>   // ACT 0=ELU, 1=tanh
__global__ __launch_bounds__(256)
void rb_dec(const float* __restrict__ x, const float* __restrict__ w,
            const float* __restrict__ bias, float* __restrict__ y)
{
    constexpr int LOUT = LIN * 2;
    const int u   = blockIdx.x * 256 + threadIdx.x;
    const int co0 = blockIdx.y * CO_PER;
    const int b   = blockIdx.z;

    float acc[CO_PER][2];
#pragma unroll
    for (int c = 0; c < CO_PER; ++c) acc[c][0] = acc[c][1] = bias[co0 + c];

    const float* xb = x + (size_t)b * CIN * LIN;
    for (int ci = 0; ci < CIN; ++ci) {
        const float* xc = xb + (size_t)ci * LIN;
        const float* wc = w + ((size_t)ci * COUT + co0) * 15;
#pragma unroll
        for (int dj = 0; dj < 8; ++dj) {
            const int j = u - 3 + dj;
            const float xv = ((unsigned)j < (unsigned)LIN) ? xc[j] : 0.f;
            const int ke = 13 - 2 * dj;
            const int ko = 14 - 2 * dj;
#pragma unroll
            for (int c = 0; c < CO_PER; ++c) {
                if (ke >= 0) acc[c][0] = fmaf(xv, wc[c * 15 + ke], acc[c][0]);
                acc[c][1] = fmaf(xv, wc[c * 15 + ko], acc[c][1]);
            }
        }
    }
#pragma unroll
    for (int c = 0; c < CO_PER; ++c) {
        float* yp = y + ((size_t)b * COUT + co0 + c) * LOUT + 2 * (size_t)u;
        if (ACT == 0) {
            yp[0] = acc[c][0] > 0.f ? acc[c][0] : expm1f(acc[c][0]);
            yp[1] = acc[c][1] > 0.f ? acc[c][1] : expm1f(acc[c][1]);
        } else {
            yp[0] = tanhf(acc[c][0]);
            yp[1] = tanhf(acc[c][1]);
        }
    }
}

// ---------------- prep: N32[c] = fl32( sum_f64 fl32(c_d^2) ) + zero loss ----------------
__global__ __launch_bounds__(64)
void rb_prep(const float* __restrict__ cb, float* __restrict__ cnormF,
             float* __restrict__ lossp)
{
    __shared__ double red[64];
    const int rrow = blockIdx.x;                 // 0..NCB*CBS-1
    const float* src = cb + (size_t)rrow * HID;
    const int lane = threadIdx.x;
    double s = 0.0;
#pragma unroll
    for (int m = 0; m < 8; ++m) {
        const float v = src[lane * 8 + m];
        const float sq = __fmul_rn(v, v);        // fl32 square, like (cb*cb)
        s += (double)sq;
    }
    red[lane] = s;
    __syncthreads();
    if (lane == 0) {
        double tot = 0.0;
        for (int i = 0; i < 64; ++i) tot += red[i];
        cnormF[rrow] = (float)tot;
        if (rrow == 0) lossp[0] = 0.f;
    }
}

// ---------------- one residual-VQ stage: f64 dot, f32-GRID scoring, f32 ST updates --------
// 512 blocks x 256 threads; block owns 64 rows x all 1024 codes; thread tile 4x4.
// Score replicates numpy f32: s = fl32( fl32(Z32 - 2*fl32(M)) + N32 ), argmin first-index.
__global__ __launch_bounds__(256)
void rb_vq(const float* __restrict__ cb,      // [CBS][HID] this stage (f32)
           const float* __restrict__ cnormF,  // [CBS] f32 (N32)
           float* __restrict__ R,             // [NB][HID][TLAT] f32, in-place residual
           float* __restrict__ Q,             // [NB][HID][TLAT] f32 quantized accumulator
           int* __restrict__ codes_out,       // stage base, [NB*TLAT]
           float* __restrict__ loss_acc, int stage)
{
    __shared__ __align__(16) float Rt[32][64];
    __shared__ __align__(16) float Ct[32][64];
    __shared__ double zpart[64][4];
    __shared__ float  Zrow[64];
    __shared__ float  sbv[64][16];
    __shared__ int    sbc[64][16];
    __shared__ int codes_l[64];

    const int tid = threadIdx.x;
    const int gr0 = blockIdx.x * 64;             // global row = b*4096 + t
    const int b   = gr0 >> 12;
    const int t0  = gr0 & 4095;
    float* Rb = R + (size_t)b * HID * TLAT + t0;
    float* Qb = Q + (size_t)b * HID * TLAT + t0;
    const int i4 = tid >> 4, j4 = tid & 15;      // row group (4 rows) / col group (4 cols)

    // ---- Z pre-pass: Z32[row] = fl32( sum_f64 fl32(r_d^2) ) ----
    {
        const int row = tid >> 2, part = tid & 3;
        double zp = 0.0;
        const int d0 = part * 128;
        for (int d = d0; d < d0 + 128; ++d) {
            const float v = Rb[(size_t)d * TLAT + row];
            const float sq = __fmul_rn(v, v);
            zp += (double)sq;
        }
        zpart[row][part] = zp;
    }
    __syncthreads();
    if (tid < 64)
        Zrow[tid] = (float)(((zpart[tid][0] + zpart[tid][1]) + zpart[tid][2]) + zpart[tid][3]);
    __syncthreads();

    float Zr4[4];
#pragma unroll
    for (int r = 0; r < 4; ++r) Zr4[r] = Zrow[i4 * 4 + r];

    float bestv[4]; int bestc[4];
#pragma unroll
    for (int r = 0; r < 4; ++r) { bestv[r] = 3.0e38f; bestc[r] = 0x7fffffff; }

    for (int ct = 0; ct < 16; ++ct) {
        const int c0 = ct * 64;
        double acc[4][4];
#pragma unroll
        for (int r = 0; r < 4; ++r)
#pragma unroll
            for (int c = 0; c < 4; ++c) acc[r][c] = 0.0;

        for (int kc = 0; kc < 16; ++kc) {
            const int k0 = kc * 32;
            __syncthreads();
#pragma unroll
            for (int l = 0; l < 8; ++l) {        // stage R tile: 32 dims x 64 rows
                const int e = l * 256 + tid;
                Rt[e >> 6][e & 63] = Rb[(size_t)(k0 + (e >> 6)) * TLAT + (e & 63)];
            }
            {                                    // stage C tile (transpose from [code][dim])
                const int cc = tid >> 2, q = (tid & 3) * 8;
                const float* s = cb + (size_t)(c0 + cc) * HID + k0 + q;
                const float4 v0 = *(const float4*)s;
                const float4 v1 = *(const float4*)(s + 4);
                Ct[q + 0][cc] = v0.x; Ct[q + 1][cc] = v0.y;
                Ct[q + 2][cc] = v0.z; Ct[q + 3][cc] = v0.w;
                Ct[q + 4][cc] = v1.x; Ct[q + 5][cc] = v1.y;
                Ct[q + 6][cc] = v1.z; Ct[q + 7][cc] = v1.w;
            }
            __syncthreads();

#pragma unroll
            for (int kk = 0; kk < 32; ++kk) {
                const float4 rv = *(const float4*)&Rt[kk][i4 * 4];
                const float4 cv = *(const float4*)&Ct[kk][j4 * 4];
                const double rd[4] = {(double)rv.x, (double)rv.y, (double)rv.z, (double)rv.w};
                const double cd[4] = {(double)cv.x, (double)cv.y, (double)cv.z, (double)cv.w};
#pragma unroll
                for (int r = 0; r < 4; ++r)
#pragma unroll
                    for (int c = 0; c < 4; ++c)
                        acc[r][c] = fma(rd[r], cd[c], acc[r][c]);
            }
        }

        // f32-grid scoring: s = fl32( fl32(Z - 2*fl32(M64)) + N32 ), ascending ci, strict <
#pragma unroll
        for (int r = 0; r < 4; ++r) {
#pragma unroll
            for (int c = 0; c < 4; ++c) {
                const int ci = c0 + j4 * 4 + c;
                const float M32 = (float)acc[r][c];
                const float T   = __fsub_rn(Zr4[r], __fadd_rn(M32, M32));  // 2*M32 exact
                const float s   = __fadd_rn(T, cnormF[ci]);
                if (s < bestv[r]) { bestv[r] = s; bestc[r] = ci; }
            }
        }
    }

    // LDS argmin across the 16 col-lanes of each row (tie -> lower index, = np.argmin)
#pragma unroll
    for (int r = 0; r < 4; ++r) { sbv[i4 * 4 + r][j4] = bestv[r]; sbc[i4 * 4 + r][j4] = bestc[r]; }
    __syncthreads();
    if (tid < 64) {
        float mv = 3.0e38f; int mc = 0x7fffffff;
        for (int jj = 0; jj < 16; ++jj) {
            const float v = sbv[tid][jj]; const int c = sbc[tid][jj];
            if (v < mv || (v == mv && c < mc)) { mv = v; mc = c; }
        }
        codes_l[tid] = mc;
    }
    __syncthreads();

    // f32 straight-through updates (faithful to reference semantics)
    float ls = 0.f;
    for (int e = tid; e < 64 * HID; e += 256) {
        const int row = e & 63, d = e >> 6;
        const size_t off = (size_t)d * TLAT + row;
        const float rr = Rb[off];
        const int c = codes_l[row];
        const float q = cb[(size_t)c * HID + d];
        const float diff  = __fsub_rn(q, rr);
        const float zqst  = __fadd_rn(rr, diff);
        ls = fmaf(diff, diff, ls);
        Rb[off] = __fsub_rn(rr, zqst);
        if (stage == 0) Qb[off] = zqst; else Qb[off] = __fadd_rn(Qb[off], zqst);
    }
    if (tid < 64) codes_out[gr0 + tid] = codes_l[tid];
#pragma unroll
    for (int off = 32; off; off >>= 1) ls += __shfl_down(ls, off, 64);
    if ((tid & 63) == 0) atomicAdd(loss_acc, ls);
}

// ---------------- single writer of d_out (f32), last dispatch ----------------
__global__ __launch_bounds__(256)
void rb_emit(const float* __restrict__ reconF, const int* __restrict__ codes_ws,
             const float* __restrict__ loss_acc, float* __restrict__ out)
{
    const int j = blockIdx.x * 256 + threadIdx.x;
    if (j >= 524288 + 1 + NCB * 32768) return;
    if (j < 524288)       out[j] = reconF[j];
    else if (j == 524288) out[j] = loss_acc[0] * 1.25f * (1.0f / 16777216.0f);
    else                  out[j] = (float)codes_ws[j - 524289];
}

extern "C" void kernel_launch(void* const* d_in, const int* in_sizes, int n_in,
                              void* d_out, int out_size, void* d_ws, size_t ws_size,
                              hipStream_t stream)
{
    float* out = (float*)d_out;

    if (n_in != 18)                                   { rb_sentinel<<<1, 256, 0, stream>>>(out, 1111.0f); return; }
    if (in_sizes[0] != 8 * 65536 || in_sizes[9] != NCB * CBS * HID ||
        in_sizes[1] != 64 * 15 || in_sizes[10] != 512 * 256 * 15)
                                                      { rb_sentinel<<<1, 256, 0, stream>>>(out, 3333.0f); return; }
    if (out_size != 524288 + 1 + NCB * 32768)         { rb_sentinel<<<1, 256, 0, stream>>>(out, 5555.0f); return; }
    if (ws_size < (size_t)133 * 1024 * 1024)          { rb_sentinel<<<1, 256, 0, stream>>>(out, 7777.0f); return; }

    const float* audio = (const float*)d_in[0];
    const float *ew[4], *eb[4], *dw[4], *db[4];
    for (int i = 0; i < 4; ++i) { ew[i] = (const float*)d_in[1 + 2 * i]; eb[i] = (const float*)d_in[2 + 2 * i]; }
    const float* cbs = (const float*)d_in[9];
    for (int i = 0; i < 4; ++i) { dw[i] = (const float*)d_in[10 + 2 * i]; db[i] = (const float*)d_in[11 + 2 * i]; }

    // ---- workspace layout (~131.2 MB; ws >= 133 MB confirmed) ----
    char* ws = (char*)d_ws;
    float*  A        = (float*)ws;                                   // [0,64MB)   enc ping / Q / dec ping
    float*  Bb       = (float*)(ws + (size_t)64 * 1024 * 1024);      // [64,128MB) enc pong / R / dec pong
    float*  reconF   = (float*)(ws + (size_t)128 * 1024 * 1024);     // 2MB
    int*    codes_ws = (int*)  (ws + (size_t)130 * 1024 * 1024);     // 1MB
    float*  cnormF   = (float*)(ws + (size_t)131 * 1024 * 1024);     // 32KB
    float*  lossp    = (float*)(ws + (size_t)131 * 1024 * 1024 + 65536);

    rb_prep<<<NCB * CBS, 64, 0, stream>>>(cbs, cnormF, lossp);

    // encoder (f64 interior, f32 storage): audio -> A -> Bb -> A -> Bb(=z=R)
    rb_enc<1,   64,  65536><<<dim3(64, 16,  NB), 256, 0, stream>>>(audio, ew[0], eb[0], A);
    rb_enc<64,  128, 32768><<<dim3(32, 32,  NB), 256, 0, stream>>>(A,  ew[1], eb[1], Bb);
    rb_enc<128, 256, 16384><<<dim3(16, 64,  NB), 256, 0, stream>>>(Bb, ew[2], eb[2], A);
    rb_enc<256, 512, 8192 ><<<dim3(8,  128, NB), 256, 0, stream>>>(A,  ew[3], eb[3], Bb);

    // residual VQ: R = Bb (f32, in-place), Q = A
    for (int i = 0; i < NCB; ++i) {
        rb_vq<<<512, 256, 0, stream>>>(cbs + (size_t)i * CBS * HID,
                                       cnormF + (size_t)i * CBS,
                                       Bb, A,
                                       codes_ws + (size_t)i * 32768,
                                       lossp, i);
    }

    // decoder (f32): A(=Q) -> Bb -> A -> Bb -> reconF
    rb_dec<512, 256, 4096,  4, 0><<<dim3(16,  64, NB), 256, 0, stream>>>(A,  dw[0], db[0], Bb);
    rb_dec<256, 128, 8192,  4, 0><<<dim3(32,  32, NB), 256, 0, stream>>>(Bb, dw[1], db[1], A);
    rb_dec<128, 64,  16384, 4, 0><<<dim3(64,  16, NB), 256, 0, stream>>>(A,  dw[2], db[2], Bb);
    rb_dec<64,  1,   32768, 1, 1><<<dim3(128, 1,  NB), 256, 0, stream>>>(Bb, dw[3], db[3], reconF);

    // single writer of d_out, last dispatch
    rb_emit<<<3073, 256, 0, stream>>>(reconF, codes_ws, lossp, out);
}